// Round 11
// baseline (583.296 us; speedup 1.0000x reference)
//
#include <hip/hip_runtime.h>
#include <hip/hip_bf16.h>

// B=8, N=2048, D=384, R=64, H=W=256.
// Inputs:  x (B,N,D) f32, segments (B,H,W) i32, prototypes (1,R,D) f32.
// Outputs (f32, concat): out (B,N,D) | segments (B,H,W) | loss (1) | C (B,N,R)
//
// Pipeline (8 dispatches):
//   memset(maskp, 64KB) ; k_proto ; k_seg (LDS-bitmask build) ; k_csim ;
//   k_lossfc ; k_off (CSR offsets from prox popcounts — scan only) ;
//   k_qks (sparse P entries: dots via MFMA + prefix-compacted scatter;
//   P is ~6% dense so dense 65MB Pbf is replaced by ~8MB of lists) ;
//   k_pv (BK=64 swizzled skeleton; A-tile rebuilt per K-step by LDS
//   scatter of ~4 entries/row) ; k_segout.
//
// History: dense k_qk pinned ~47us (65MB mostly-zero writes). k_nbr v1
// (lane-serial scalar dots) = 80.9us, MfmaUtil 0, VALUBusy 30 — wrong pipe.
// v2 splits: k_off (scan, ~4us) + k_qks (MFMA dots + popc-prefix scatter).
#define NB 8
#define NN 2048
#define ND 384
#define NR 64
#define OUT_ELEMS (NB*NN*ND)        // 6291456
#define SEG_ELEMS (NB*256*256)      // 524288
#define NBLK_LOSS (NB*NN/4)         // 4096
#define NBCAP 384                   // per-row entry cap (mean ~127)

typedef float  f32x4  __attribute__((ext_vector_type(4)));
typedef short  bf16x8 __attribute__((ext_vector_type(8)));

__device__ inline float wsum(float v){
  #pragma unroll
  for(int o=32;o;o>>=1) v += __shfl_xor(v,o,64);
  return v;
}
__device__ inline float wmax(float v){
  #pragma unroll
  for(int o=32;o;o>>=1) v = fmaxf(v,__shfl_xor(v,o,64));
  return v;
}
__device__ inline unsigned short f2bf(float f){
  unsigned u = __float_as_uint(f);
  return (unsigned short)((u + 0x8000u) >> 16);
}

// async global->LDS, 16 B per lane; LDS dest is wave-uniform base + lane*16
__device__ __forceinline__ void gl2lds16(const unsigned short* g, unsigned short* s){
  __builtin_amdgcn_global_load_lds(
      (const __attribute__((address_space(1))) unsigned int*)g,
      (__attribute__((address_space(3))) unsigned int*)s,
      16, 0, 0);
}

// ---- normalize prototypes -> kn (f32, unit rows) ----
__global__ void k_proto(const float* __restrict__ protos, float* __restrict__ kn){
  int r = blockIdx.x, l = threadIdx.x;
  float v[6]; float ss = 0.f;
  #pragma unroll
  for(int i=0;i<6;i++){ v[i] = protos[r*ND + l*6 + i]; ss += v[i]*v[i]; }
  ss = wsum(ss);
  float inv = 1.f / fmaxf(sqrtf(ss), 1e-8f);
  #pragma unroll
  for(int i=0;i<6;i++) kn[r*ND + l*6 + i] = v[i]*inv;
}

// ---- segments -> node mask + prox bitmask rows, built in LDS ----
// grid 256: b=bid&7 (batch), rg=bid>>3 (64-node range). 1024 threads.
__global__ __launch_bounds__(1024) void k_seg(const int* __restrict__ seg,
                                              float* __restrict__ mask,
                                              unsigned* __restrict__ prox){
  __shared__ unsigned lm[64*64];    // 16 KB
  int tid = threadIdx.x;
  int b  = blockIdx.x & 7;
  int rg = blockIdx.x >> 3;         // 0..31
  int base = rg << 6;
  for(int i=tid; i<64*64; i+=1024) lm[i] = 0u;
  __syncthreads();
  const int* sb = seg + b*65536;

#define PAIR(S, S2) { \
    if((S) != (S2) && (S) != 0 && (S2) != 0){ \
      if(((S )>>6)==rg) atomicOr(&lm[(((S )&63)<<6) + ((S2)>>5)], 1u<<((S2)&31)); \
      if(((S2)>>6)==rg) atomicOr(&lm[(((S2)&63)<<6) + ((S )>>5)], 1u<<((S )&31)); \
    } }

  #pragma unroll 1
  for(int it=0; it<16; ++it){
    int g = it*1024 + tid;          // int4 group index in [0,16384)
    int p = g*4;
    int i = g >> 6;                 // row 0..255
    int j = (g & 63)*4;             // col 0,4,...,252
    int4 a = *(const int4*)(sb + p);
    if((a.x>>6)==rg) mask[(b<<11) + a.x] = 1.f;
    if((a.y>>6)==rg) mask[(b<<11) + a.y] = 1.f;
    if((a.z>>6)==rg) mask[(b<<11) + a.z] = 1.f;
    if((a.w>>6)==rg) mask[(b<<11) + a.w] = 1.f;
    PAIR(a.x, a.y); PAIR(a.y, a.z); PAIR(a.z, a.w);
    if(j < 252){
      int n = sb[p + 4];
      PAIR(a.w, n);
    }
    if(i < 255){
      int4 v = *(const int4*)(sb + p + 256);
      PAIR(a.x, v.x); PAIR(a.y, v.y); PAIR(a.z, v.z); PAIR(a.w, v.w);
    }
  }
#undef PAIR
  __syncthreads();
  unsigned* dst = prox + ((size_t)(b<<11) + base)*64;
  *(uint4*)(dst + tid*4) = *(const uint4*)&lm[tid*4];
}

// ---- Csim GEMM: writes NORMALIZED s, colsum partials, bf16 xT ----
__global__ __launch_bounds__(256) void k_csim(const float* __restrict__ x,
                                              const float* __restrict__ kn,
                                              float* __restrict__ Sout,
                                              unsigned short* __restrict__ xTbf,
                                              float* __restrict__ part){
  __shared__ float xT[32*68];
  __shared__ float kT[32*68];
  __shared__ float xinvS[64];
  __shared__ float csh[16*64];
  int t = threadIdx.x;
  int m0 = blockIdx.x * 64;
  float acc[4][4] = {};
  int mload = t>>2, koff = (t&3)*8;
  int mb = (t>>4)*4, rb = (t&15)*4;
  float ssq = 0.f;
  for(int c=0;c<12;c++){
    int k0 = c*32;
    __syncthreads();
    const float4* xg = (const float4*)(x + (size_t)(m0+mload)*ND + k0 + koff);
    float4 a = xg[0], bq = xg[1];
    ssq += a.x*a.x + a.y*a.y + a.z*a.z + a.w*a.w
         + bq.x*bq.x + bq.y*bq.y + bq.z*bq.z + bq.w*bq.w;
    xT[(koff+0)*68+mload]=a.x;  xT[(koff+1)*68+mload]=a.y;  xT[(koff+2)*68+mload]=a.z;  xT[(koff+3)*68+mload]=a.w;
    xT[(koff+4)*68+mload]=bq.x; xT[(koff+5)*68+mload]=bq.y; xT[(koff+6)*68+mload]=bq.z; xT[(koff+7)*68+mload]=bq.w;
    const float4* kg = (const float4*)(kn + mload*ND + k0 + koff);
    float4 ka = kg[0], kb = kg[1];
    kT[(koff+0)*68+mload]=ka.x; kT[(koff+1)*68+mload]=ka.y; kT[(koff+2)*68+mload]=ka.z; kT[(koff+3)*68+mload]=ka.w;
    kT[(koff+4)*68+mload]=kb.x; kT[(koff+5)*68+mload]=kb.y; kT[(koff+6)*68+mload]=kb.z; kT[(koff+7)*68+mload]=kb.w;
    __syncthreads();
    {
      int k2 = t>>3, mo = (t&7)*8;
      const float* src = &xT[k2*68 + mo];
      float4 aa = *(const float4*)src;
      float4 bb = *(const float4*)(src+4);
      uint4 o;
      o.x = (unsigned)f2bf(aa.x) | ((unsigned)f2bf(aa.y)<<16);
      o.y = (unsigned)f2bf(aa.z) | ((unsigned)f2bf(aa.w)<<16);
      o.z = (unsigned)f2bf(bb.x) | ((unsigned)f2bf(bb.y)<<16);
      o.w = (unsigned)f2bf(bb.z) | ((unsigned)f2bf(bb.w)<<16);
      int bb2 = m0 >> 11, ml = m0 & 2047;
      *(uint4*)(xTbf + ((size_t)(bb2*ND + k0 + k2))*NN + ml + mo) = o;
    }
    for(int k=0;k<32;k++){
      float xv[4], kv[4];
      *(float4*)xv = *(const float4*)&xT[k*68+mb];
      *(float4*)kv = *(const float4*)&kT[k*68+rb];
      #pragma unroll
      for(int mi=0;mi<4;mi++)
        #pragma unroll
        for(int ri=0;ri<4;ri++) acc[mi][ri] += xv[mi]*kv[ri];
    }
  }
  ssq += __shfl_xor(ssq,1,64);
  ssq += __shfl_xor(ssq,2,64);
  if((t&3)==0) xinvS[mload] = 1.f / fmaxf(sqrtf(ssq), 1e-8f);
  __syncthreads();
  float sv[4][4];
  #pragma unroll
  for(int mi=0;mi<4;mi++){
    float xin = xinvS[mb+mi];
    float rsum = 0.f;
    #pragma unroll
    for(int ri=0;ri<4;ri++){
      float vv = (acc[mi][ri]*xin + 1.f)*0.5f;
      sv[mi][ri] = vv; rsum += vv;
    }
    rsum += __shfl_xor(rsum,1,64);
    rsum += __shfl_xor(rsum,2,64);
    rsum += __shfl_xor(rsum,4,64);
    rsum += __shfl_xor(rsum,8,64);
    float inv = 1.f/rsum;
    #pragma unroll
    for(int ri=0;ri<4;ri++) sv[mi][ri] *= inv;
    *(float4*)&Sout[(size_t)(m0+mb+mi)*NR + rb] = *(const float4*)sv[mi];
  }
  {
    float4 pc;
    pc.x = sv[0][0]+sv[1][0]+sv[2][0]+sv[3][0];
    pc.y = sv[0][1]+sv[1][1]+sv[2][1]+sv[3][1];
    pc.z = sv[0][2]+sv[1][2]+sv[2][2]+sv[3][2];
    pc.w = sv[0][3]+sv[1][3]+sv[2][3]+sv[3][3];
    *(float4*)&csh[(t>>4)*64 + rb] = pc;
  }
  __syncthreads();
  if(t < 64){
    float a = 0.f;
    #pragma unroll
    for(int g=0;g<16;g++) a += csh[g*64 + t];
    part[(size_t)blockIdx.x*64 + t] = a;        // part[b*32+chunk][r]
  }
}

// ---- DEC KL loss (partial stores) + C=softmax(s) in place + Kbf ----
__global__ void k_lossfc(float* Smat, const float* __restrict__ part,
                         const float* __restrict__ mask,
                         float* __restrict__ klp, float* __restrict__ mp,
                         unsigned short* __restrict__ Kbf){
  __shared__ float shk[4], shm[4];
  int w = threadIdx.x>>6, l = threadIdx.x&63;
  int node = blockIdx.x*4 + w;
  int b = node >> 11;
  float s = Smat[(size_t)node*NR + l];
  float csm = 0.f;
  #pragma unroll
  for(int c=0;c<32;c++) csm += part[(size_t)((b<<5)+c)*64 + l];
  float p = s*s/(csm + 1e-8f);
  float ps = wsum(p);
  float P = p/(ps + 1e-8f);
  float term = P*(logf(P + 1e-8f) - logf(s + 1e-8f));
  float kl = wsum(term);
  if(l==0){ float mv = mask[node]; shk[w] = kl*mv; shm[w] = mv; }
  float mx = wmax(s);
  float e = expf(s - mx);
  float Z = wsum(e);
  float c = e / Z;
  float cn2 = wsum(c*c);
  Smat[(size_t)node*NR + l] = c;
  Kbf[(size_t)node*NR + l] = f2bf(c * rsqrtf(cn2));
  __syncthreads();
  if(threadIdx.x==0){
    klp[blockIdx.x] = shk[0]+shk[1]+shk[2]+shk[3];
    mp [blockIdx.x] = shm[0]+shm[1]+shm[2]+shm[3];
  }
}

// ---- k_off: CSR offsets from prox popcounts (scan only, no dots) ----
// One wave per node row n. Lane L owns prox word L; diag bit OR'd in.
// off[n][t] = exclusive prefix at lane 2t ; off[n][32] = total.
__global__ __launch_bounds__(256) void k_off(const unsigned* __restrict__ prox,
                                             unsigned short* __restrict__ off){
  int w = threadIdx.x>>6, L = threadIdx.x&63;
  int n = blockIdx.x*4 + w;                    // global row in [0, NB*NN)
  int node = n & (NN-1);
  unsigned word = prox[(size_t)n*64 + L];
  if(L == (node>>5)) word |= 1u << (node&31);  // diagonal always present
  int pc = __popc(word);
  int pre = pc;                                 // inclusive scan
  #pragma unroll
  for(int o=1;o<64;o<<=1){
    int v = __shfl_up(pre, o, 64);
    if(L >= o) pre += v;
  }
  int base = pre - pc;                          // exclusive
  if((L&1)==0) off[(size_t)n*33 + (L>>1)] = (unsigned short)base;
  if(L==63)    off[(size_t)n*33 + 32]     = (unsigned short)pre;
}

// ---- k_qks: sparse P entries — dots via MFMA + prefix-compacted scatter ----
// grid 4096: b=bid&7, qt=(bid>>3)&31, kc=bid>>8 (chunk of 8 kts).
// Wave w owns rows qt*64+w*16..+15 (A-frags af0/af1 loop-invariant).
// Per kt: 8 B-frag loads (L2-hot Kbf) + 8 MFMA -> pacc[f][r] = P[row][col=
// f*16+li]. prox 16-bit fragment mask (uniform within the 16-lane group)
// gives slot = base[r] + popc(m16 & below_li); set lanes write
// (col<<16)|bf16(val). base[r] starts at off[row][kc*8] and accumulates
// popcounts -> slots exactly match k_off/k_pv's CSR ranges. No barriers.
__global__ __launch_bounds__(256) void k_qks(const unsigned short* __restrict__ Kbf,
                                             const unsigned* __restrict__ prox,
                                             const unsigned short* __restrict__ off,
                                             unsigned* __restrict__ nbr){
  int tid = threadIdx.x;
  int w = tid>>6, l = tid&63, q = l>>4, li = l&15;
  int b  = blockIdx.x & 7;
  int qt = (blockIdx.x>>3) & 31;
  int kc = blockIdx.x >> 8;                   // 0..3 (chunk of 8 kts)
  const unsigned short* Kb = Kbf + (size_t)b*NN*NR;

  int arow = qt*64 + w*16 + li;
  bf16x8 af0 = *(const bf16x8*)(Kb + (size_t)arow*NR + q*8);
  bf16x8 af1 = *(const bf16x8*)(Kb + (size_t)arow*NR + 32 + q*8);

  // rows handled by this lane's (q)-group: lrow = w*16+q*4+r
  int base[4];
  #pragma unroll
  for(int r=0;r<4;r++)
    base[r] = off[(size_t)(b*NN + qt*64 + w*16 + q*4 + r)*33 + kc*8];

  unsigned below = (1u<<li) - 1u;

  #pragma unroll 1
  for(int kt = kc*8; kt < kc*8 + 8; ++kt){
    uint2 mw[4];
    #pragma unroll
    for(int r=0;r<4;r++)
      mw[r] = *(const uint2*)(prox + ((size_t)(b*NN + qt*64 + w*16 + q*4 + r))*64 + kt*2);
    if(qt==kt){
      #pragma unroll
      for(int r=0;r<4;r++){
        int lrow = w*16 + q*4 + r;
        if((lrow>>5)==0) mw[r].x |= 1u<<(lrow&31); else mw[r].y |= 1u<<(lrow&31);
      }
    }
    bf16x8 b0[4], b1[4];
    #pragma unroll
    for(int f=0;f<4;f++){
      const unsigned short* p = Kb + (size_t)(kt*64 + f*16 + li)*NR + q*8;
      b0[f] = *(const bf16x8*)p;
      b1[f] = *(const bf16x8*)(p + 32);
    }
    f32x4 pacc[4] = {(f32x4)(0.f),(f32x4)(0.f),(f32x4)(0.f),(f32x4)(0.f)};
    #pragma unroll
    for(int f=0;f<4;f++){
      pacc[f] = __builtin_amdgcn_mfma_f32_16x16x32_bf16(af0, b0[f], pacc[f], 0,0,0);
      pacc[f] = __builtin_amdgcn_mfma_f32_16x16x32_bf16(af1, b1[f], pacc[f], 0,0,0);
    }
    // compaction: per row r, fragments f ascending keep col order per tile
    #pragma unroll
    for(int r=0;r<4;r++){
      unsigned* nrow = nbr + (size_t)(b*NN + qt*64 + w*16 + q*4 + r)*NBCAP;
      #pragma unroll
      for(int f=0;f<4;f++){
        unsigned wd  = (f<2) ? mw[r].x : mw[r].y;
        unsigned m16 = (wd >> ((f&1)*16)) & 0xFFFFu;
        if(m16){
          if((m16 >> li) & 1u){
            int idx = base[r] + __popc(m16 & below);
            if(idx < NBCAP)
              nrow[idx] = ((unsigned)(kt*64 + f*16 + li) << 16) | (unsigned)f2bf(pacc[f][r]);
          }
          base[r] += __popc(m16);
        }
      }
    }
  }
}

// ---- k_pv: out = diag(1/(P*1)) P X. BK=64 swizzled skeleton; A-tile
// rebuilt per K-step by LDS scatter of sparse entries (P never in HBM) ----
__global__ __launch_bounds__(256, 3) void k_pv(const unsigned* __restrict__ nbr,
                                               const unsigned short* __restrict__ off,
                                               const unsigned short* __restrict__ xTbf,
                                               float* __restrict__ out){
  __shared__ unsigned short Al[64*64];     // 8 KB  P-tile (scatter-built)
  __shared__ unsigned short Bl[128*64];    // 16 KB xT tile
  __shared__ unsigned short offL[64*33];   // 4.2 KB CSR offsets
  int tid = threadIdx.x;
  int w = tid>>6, l = tid&63, q = l>>4, li = l&15;
  int b  = blockIdx.x & 7;
  int mt = (blockIdx.x>>3) & 31;
  int ct = blockIdx.x >> 8;                // 0..2
  int m0 = mt*64;
  int d0 = ct*128;
  const unsigned short* xTb = xTbf + (size_t)b*ND*NN;

  int wr = w & 1, wc = w >> 1;

  int lrow8 = l>>3;
  int sgel  = ((l&7) ^ lrow8) * 8;
  const unsigned short* gsrc[4];
  unsigned short* ldst[4];
  #pragma unroll
  for(int j=0;j<4;j++){
    int id = w*4 + j;
    ldst[j] = Bl + id*512;
    gsrc[j] = xTb + (size_t)(d0 + id*8 + lrow8)*NN + sgel;
  }

  int srow = tid>>2, g = tid&3;
  int r7s  = srow & 7;
  const unsigned* ebase = nbr + (size_t)(b*NN + m0 + srow)*NBCAP;
  for(int j=g; j<33; j+=4)
    offL[srow*33 + j] = off[(size_t)(b*NN + m0 + srow)*33 + j];

  f32x4 acc[2][4];
  #pragma unroll
  for(int nc=0;nc<2;nc++)
    #pragma unroll
    for(int t=0;t<4;t++) acc[nc][t] = (f32x4)(0.f);
  f32x4 rs[2] = {(f32x4)(0.f),(f32x4)(0.f)};
  bf16x8 ones;
  #pragma unroll
  for(int i=0;i<8;i++) ones[i] = (short)0x3F80;   // bf16 1.0

  int r7 = li & 7;
  for(int k0=0; k0<NN; k0+=64){
    int t = k0 >> 6;
    __syncthreads();                       // A: prev PV reads done (+offL on t=0)
    {
      uint4 z = {0,0,0,0};
      *(uint4*)&Al[tid*16]     = z;
      *(uint4*)&Al[tid*16 + 8] = z;
    }
    __syncthreads();                       // Z: zeros visible
    #pragma unroll
    for(int j=0;j<4;j++) gl2lds16(gsrc[j] + k0, ldst[j]);
    {
      int s0 = offL[srow*33 + t];
      int s1 = offL[srow*33 + t + 1];
      if(s1 > NBCAP) s1 = NBCAP;
      for(int i=s0+g; i<s1; i+=4){
        unsigned e = ebase[i];
        int col = (int)(e >> 16) - k0;     // in [0,64)
        int phys = (((col>>3) ^ r7s) << 3) | (col & 7);
        Al[srow*64 + phys] = (unsigned short)(e & 0xffffu);
      }
    }
    __syncthreads();                       // B: Al visible + Bl drained

    #pragma unroll
    for(int s=0;s<2;s++){
      int ps = ((s*4 + q) ^ r7) * 8;       // swizzled read seg (elements)
      bf16x8 a0 = *(const bf16x8*)&Al[(wr*32 +      li)*64 + ps];
      bf16x8 a1 = *(const bf16x8*)&Al[(wr*32 + 16 + li)*64 + ps];
      bf16x8 bv[4];
      #pragma unroll
      for(int t2=0;t2<4;t2++)
        bv[t2] = *(const bf16x8*)&Bl[(wc*64 + t2*16 + li)*64 + ps];
      #pragma unroll
      for(int t2=0;t2<4;t2++){
        acc[0][t2] = __builtin_amdgcn_mfma_f32_16x16x32_bf16(a0, bv[t2], acc[0][t2], 0,0,0);
        acc[1][t2] = __builtin_amdgcn_mfma_f32_16x16x32_bf16(a1, bv[t2], acc[1][t2], 0,0,0);
      }
      rs[0] = __builtin_amdgcn_mfma_f32_16x16x32_bf16(a0, ones, rs[0], 0,0,0);
      rs[1] = __builtin_amdgcn_mfma_f32_16x16x32_bf16(a1, ones, rs[1], 0,0,0);
    }
  }

  #pragma unroll
  for(int nc=0;nc<2;nc++)
    #pragma unroll
    for(int r=0;r<4;r++){
      int row = m0 + wr*32 + nc*16 + q*4 + r;
      float inv = 1.f/(rs[nc][r] + 1e-8f);
      float* orow = out + ((size_t)(b*NN + row))*ND + d0 + wc*64;
      #pragma unroll
      for(int t2=0;t2<4;t2++)
        orow[t2*16 + li] = acc[nc][t2][r] * inv;
    }
}

// ---- segout; block 0 also reduces the loss partials ----
__global__ void k_segout(const int* __restrict__ seg, float* __restrict__ o,
                         const float* __restrict__ klp, const float* __restrict__ mp,
                         float* __restrict__ outLoss){
  int tid = threadIdx.x;
  int i = blockIdx.x*256 + tid;
  o[i] = (float)seg[i];
  if(blockIdx.x==0){
    __shared__ float sa[4], sm[4];
    float a=0.f, m=0.f;
    for(int k=tid; k<NBLK_LOSS; k+=256){ a += klp[k]; m += mp[k]; }
    a = wsum(a); m = wsum(m);
    if((tid&63)==0){ sa[tid>>6]=a; sm[tid>>6]=m; }
    __syncthreads();
    if(tid==0)
      outLoss[0] = (sa[0]+sa[1]+sa[2]+sa[3])/((sm[0]+sm[1]+sm[2]+sm[3])+1e-8f);
  }
}

extern "C" void kernel_launch(void* const* d_in, const int* in_sizes, int n_in,
                              void* d_out, int out_size, void* d_ws, size_t ws_size,
                              hipStream_t stream) {
  const float* x      = (const float*)d_in[0];
  const int*   seg    = (const int*)d_in[1];
  const float* protos = (const float*)d_in[2];

  float* out     = (float*)d_out;                  // (B,N,D)
  float* outSeg  = out + OUT_ELEMS;                // (B,H,W)
  float* outLoss = outSeg + SEG_ELEMS;             // scalar
  float* outC    = outLoss + 1;                    // (B,N,R)

  // ws layout (sparse P lists live in the old Pbf region)
  unsigned short* xTbf = (unsigned short*)d_ws;            // 8*384*2048 bf16 (12.6MB)
  unsigned short* Kbf  = xTbf + (size_t)NB*ND*NN;          // 8*2048*64 bf16 (2MB)
  unsigned short* Pbf  = Kbf + (size_t)NB*NN*NR;           // 64MB region, reused:
  unsigned*       nbr  = (unsigned*)Pbf;                   //   16384*384 u32 (25MB)
  unsigned short* off  = (unsigned short*)(nbr + (size_t)NB*NN*NBCAP); // 16384*33 u16
  float* kn      = (float*)(Pbf + (size_t)NB*NN*NN);       // 24576 f32
  float* maskp   = kn + NR*ND;                             // 16384  -- zero region (64KB)
  unsigned* prox = (unsigned*)(maskp + NB*NN);             // 8*2048*64 u32 (4MB, fully written)
  float* part    = (float*)(prox + (size_t)NB*NN*64);      // 8*32*64 (fully written)
  float* klp     = part + NB*32*64;                        // 4096 (fully written)
  float* mp      = klp + NBLK_LOSS;                        // 4096 (fully written)

  // only maskp needs zeroing (prox/nbr/off are fully written before use)
  hipMemsetAsync(maskp, 0, (size_t)NB*NN*4, stream);

  k_proto <<<dim3(NR),           dim3(64),   0, stream>>>(protos, kn);
  k_seg   <<<dim3(256),          dim3(1024), 0, stream>>>(seg, maskp, prox);
  k_csim  <<<dim3(NB*NN/64),     dim3(256),  0, stream>>>(x, kn, outC, xTbf, part);
  k_lossfc<<<dim3(NBLK_LOSS),    dim3(256),  0, stream>>>(outC, part, maskp, klp, mp, Kbf);
  k_off   <<<dim3(NB*NN/4),      dim3(256),  0, stream>>>(prox, off);
  k_qks   <<<dim3(4096),         dim3(256),  0, stream>>>(Kbf, prox, off, nbr);
  k_pv    <<<dim3(768),          dim3(256),  0, stream>>>(nbr, off, xTbf, out);
  k_segout<<<dim3(SEG_ELEMS/256),dim3(256),  0, stream>>>(seg, outSeg, klp, mp, outLoss);
}

// Round 12
// 238.106 us; speedup vs baseline: 2.4497x; 2.4497x over previous
//
#include <hip/hip_runtime.h>
#include <hip/hip_bf16.h>

// B=8, N=2048, D=384, R=64, H=W=256.
// Inputs:  x (B,N,D) f32, segments (B,H,W) i32, prototypes (1,R,D) f32.
// Outputs (f32, concat): out (B,N,D) | segments (B,H,W) | loss (1) | C (B,N,R)
//
// Pipeline (8 dispatches):
//   memset(maskp, 64KB) ; k_proto ; k_seg (LDS-bitmask build) ; k_csim ;
//   k_lossfc ; k_off (CSR offsets from prox popcounts) ; k_qks (sparse P
//   entries: dots via MFMA + popc-prefix-compacted scatter; P is ~6% dense)
//   ; k_pv (BK=64 swizzled skeleton; A-tile rebuilt per K-step by LDS
//   scatter of ~4 entries/row; 2 barriers/step) ; k_segout.
//
// Round-11 post-mortem: k_qks was launched grid 4096 but decomposes as
// 8b x 32qt x 4kc = 1024 — rogue blocks (kc>=4) read OOB offsets/prox and
// scattered col-garbage into nbr; k_pv's unguarded `col-k0` then wrote
// past Al into Bl/offL (LDS corruption -> absmax 1.53, 330us scatter
// storms). Fix: grid 1024 + col<64 guard. Also: zero-Al now done by the
// same 4-lane group that scatters the row (same-wave DS ordering) -> the
// third barrier is gone, back to the proven 2-barrier skeleton.
#define NB 8
#define NN 2048
#define ND 384
#define NR 64
#define OUT_ELEMS (NB*NN*ND)        // 6291456
#define SEG_ELEMS (NB*256*256)      // 524288
#define NBLK_LOSS (NB*NN/4)         // 4096
#define NBCAP 384                   // per-row entry cap (mean ~127)

typedef float  f32x4  __attribute__((ext_vector_type(4)));
typedef short  bf16x8 __attribute__((ext_vector_type(8)));

__device__ inline float wsum(float v){
  #pragma unroll
  for(int o=32;o;o>>=1) v += __shfl_xor(v,o,64);
  return v;
}
__device__ inline float wmax(float v){
  #pragma unroll
  for(int o=32;o;o>>=1) v = fmaxf(v,__shfl_xor(v,o,64));
  return v;
}
__device__ inline unsigned short f2bf(float f){
  unsigned u = __float_as_uint(f);
  return (unsigned short)((u + 0x8000u) >> 16);
}

// async global->LDS, 16 B per lane; LDS dest is wave-uniform base + lane*16
__device__ __forceinline__ void gl2lds16(const unsigned short* g, unsigned short* s){
  __builtin_amdgcn_global_load_lds(
      (const __attribute__((address_space(1))) unsigned int*)g,
      (__attribute__((address_space(3))) unsigned int*)s,
      16, 0, 0);
}

// ---- normalize prototypes -> kn (f32, unit rows) ----
__global__ void k_proto(const float* __restrict__ protos, float* __restrict__ kn){
  int r = blockIdx.x, l = threadIdx.x;
  float v[6]; float ss = 0.f;
  #pragma unroll
  for(int i=0;i<6;i++){ v[i] = protos[r*ND + l*6 + i]; ss += v[i]*v[i]; }
  ss = wsum(ss);
  float inv = 1.f / fmaxf(sqrtf(ss), 1e-8f);
  #pragma unroll
  for(int i=0;i<6;i++) kn[r*ND + l*6 + i] = v[i]*inv;
}

// ---- segments -> node mask + prox bitmask rows, built in LDS ----
// grid 256: b=bid&7 (batch), rg=bid>>3 (64-node range). 1024 threads.
__global__ __launch_bounds__(1024) void k_seg(const int* __restrict__ seg,
                                              float* __restrict__ mask,
                                              unsigned* __restrict__ prox){
  __shared__ unsigned lm[64*64];    // 16 KB
  int tid = threadIdx.x;
  int b  = blockIdx.x & 7;
  int rg = blockIdx.x >> 3;         // 0..31
  int base = rg << 6;
  for(int i=tid; i<64*64; i+=1024) lm[i] = 0u;
  __syncthreads();
  const int* sb = seg + b*65536;

#define PAIR(S, S2) { \
    if((S) != (S2) && (S) != 0 && (S2) != 0){ \
      if(((S )>>6)==rg) atomicOr(&lm[(((S )&63)<<6) + ((S2)>>5)], 1u<<((S2)&31)); \
      if(((S2)>>6)==rg) atomicOr(&lm[(((S2)&63)<<6) + ((S )>>5)], 1u<<((S )&31)); \
    } }

  #pragma unroll 1
  for(int it=0; it<16; ++it){
    int g = it*1024 + tid;          // int4 group index in [0,16384)
    int p = g*4;
    int i = g >> 6;                 // row 0..255
    int j = (g & 63)*4;             // col 0,4,...,252
    int4 a = *(const int4*)(sb + p);
    if((a.x>>6)==rg) mask[(b<<11) + a.x] = 1.f;
    if((a.y>>6)==rg) mask[(b<<11) + a.y] = 1.f;
    if((a.z>>6)==rg) mask[(b<<11) + a.z] = 1.f;
    if((a.w>>6)==rg) mask[(b<<11) + a.w] = 1.f;
    PAIR(a.x, a.y); PAIR(a.y, a.z); PAIR(a.z, a.w);
    if(j < 252){
      int n = sb[p + 4];
      PAIR(a.w, n);
    }
    if(i < 255){
      int4 v = *(const int4*)(sb + p + 256);
      PAIR(a.x, v.x); PAIR(a.y, v.y); PAIR(a.z, v.z); PAIR(a.w, v.w);
    }
  }
#undef PAIR
  __syncthreads();
  unsigned* dst = prox + ((size_t)(b<<11) + base)*64;
  *(uint4*)(dst + tid*4) = *(const uint4*)&lm[tid*4];
}

// ---- Csim GEMM: writes NORMALIZED s, colsum partials, bf16 xT ----
__global__ __launch_bounds__(256) void k_csim(const float* __restrict__ x,
                                              const float* __restrict__ kn,
                                              float* __restrict__ Sout,
                                              unsigned short* __restrict__ xTbf,
                                              float* __restrict__ part){
  __shared__ float xT[32*68];
  __shared__ float kT[32*68];
  __shared__ float xinvS[64];
  __shared__ float csh[16*64];
  int t = threadIdx.x;
  int m0 = blockIdx.x * 64;
  float acc[4][4] = {};
  int mload = t>>2, koff = (t&3)*8;
  int mb = (t>>4)*4, rb = (t&15)*4;
  float ssq = 0.f;
  for(int c=0;c<12;c++){
    int k0 = c*32;
    __syncthreads();
    const float4* xg = (const float4*)(x + (size_t)(m0+mload)*ND + k0 + koff);
    float4 a = xg[0], bq = xg[1];
    ssq += a.x*a.x + a.y*a.y + a.z*a.z + a.w*a.w
         + bq.x*bq.x + bq.y*bq.y + bq.z*bq.z + bq.w*bq.w;
    xT[(koff+0)*68+mload]=a.x;  xT[(koff+1)*68+mload]=a.y;  xT[(koff+2)*68+mload]=a.z;  xT[(koff+3)*68+mload]=a.w;
    xT[(koff+4)*68+mload]=bq.x; xT[(koff+5)*68+mload]=bq.y; xT[(koff+6)*68+mload]=bq.z; xT[(koff+7)*68+mload]=bq.w;
    const float4* kg = (const float4*)(kn + mload*ND + k0 + koff);
    float4 ka = kg[0], kb = kg[1];
    kT[(koff+0)*68+mload]=ka.x; kT[(koff+1)*68+mload]=ka.y; kT[(koff+2)*68+mload]=ka.z; kT[(koff+3)*68+mload]=ka.w;
    kT[(koff+4)*68+mload]=kb.x; kT[(koff+5)*68+mload]=kb.y; kT[(koff+6)*68+mload]=kb.z; kT[(koff+7)*68+mload]=kb.w;
    __syncthreads();
    {
      int k2 = t>>3, mo = (t&7)*8;
      const float* src = &xT[k2*68 + mo];
      float4 aa = *(const float4*)src;
      float4 bb = *(const float4*)(src+4);
      uint4 o;
      o.x = (unsigned)f2bf(aa.x) | ((unsigned)f2bf(aa.y)<<16);
      o.y = (unsigned)f2bf(aa.z) | ((unsigned)f2bf(aa.w)<<16);
      o.z = (unsigned)f2bf(bb.x) | ((unsigned)f2bf(bb.y)<<16);
      o.w = (unsigned)f2bf(bb.z) | ((unsigned)f2bf(bb.w)<<16);
      int bb2 = m0 >> 11, ml = m0 & 2047;
      *(uint4*)(xTbf + ((size_t)(bb2*ND + k0 + k2))*NN + ml + mo) = o;
    }
    for(int k=0;k<32;k++){
      float xv[4], kv[4];
      *(float4*)xv = *(const float4*)&xT[k*68+mb];
      *(float4*)kv = *(const float4*)&kT[k*68+rb];
      #pragma unroll
      for(int mi=0;mi<4;mi++)
        #pragma unroll
        for(int ri=0;ri<4;ri++) acc[mi][ri] += xv[mi]*kv[ri];
    }
  }
  ssq += __shfl_xor(ssq,1,64);
  ssq += __shfl_xor(ssq,2,64);
  if((t&3)==0) xinvS[mload] = 1.f / fmaxf(sqrtf(ssq), 1e-8f);
  __syncthreads();
  float sv[4][4];
  #pragma unroll
  for(int mi=0;mi<4;mi++){
    float xin = xinvS[mb+mi];
    float rsum = 0.f;
    #pragma unroll
    for(int ri=0;ri<4;ri++){
      float vv = (acc[mi][ri]*xin + 1.f)*0.5f;
      sv[mi][ri] = vv; rsum += vv;
    }
    rsum += __shfl_xor(rsum,1,64);
    rsum += __shfl_xor(rsum,2,64);
    rsum += __shfl_xor(rsum,4,64);
    rsum += __shfl_xor(rsum,8,64);
    float inv = 1.f/rsum;
    #pragma unroll
    for(int ri=0;ri<4;ri++) sv[mi][ri] *= inv;
    *(float4*)&Sout[(size_t)(m0+mb+mi)*NR + rb] = *(const float4*)sv[mi];
  }
  {
    float4 pc;
    pc.x = sv[0][0]+sv[1][0]+sv[2][0]+sv[3][0];
    pc.y = sv[0][1]+sv[1][1]+sv[2][1]+sv[3][1];
    pc.z = sv[0][2]+sv[1][2]+sv[2][2]+sv[3][2];
    pc.w = sv[0][3]+sv[1][3]+sv[2][3]+sv[3][3];
    *(float4*)&csh[(t>>4)*64 + rb] = pc;
  }
  __syncthreads();
  if(t < 64){
    float a = 0.f;
    #pragma unroll
    for(int g=0;g<16;g++) a += csh[g*64 + t];
    part[(size_t)blockIdx.x*64 + t] = a;        // part[b*32+chunk][r]
  }
}

// ---- DEC KL loss (partial stores) + C=softmax(s) in place + Kbf ----
__global__ void k_lossfc(float* Smat, const float* __restrict__ part,
                         const float* __restrict__ mask,
                         float* __restrict__ klp, float* __restrict__ mp,
                         unsigned short* __restrict__ Kbf){
  __shared__ float shk[4], shm[4];
  int w = threadIdx.x>>6, l = threadIdx.x&63;
  int node = blockIdx.x*4 + w;
  int b = node >> 11;
  float s = Smat[(size_t)node*NR + l];
  float csm = 0.f;
  #pragma unroll
  for(int c=0;c<32;c++) csm += part[(size_t)((b<<5)+c)*64 + l];
  float p = s*s/(csm + 1e-8f);
  float ps = wsum(p);
  float P = p/(ps + 1e-8f);
  float term = P*(logf(P + 1e-8f) - logf(s + 1e-8f));
  float kl = wsum(term);
  if(l==0){ float mv = mask[node]; shk[w] = kl*mv; shm[w] = mv; }
  float mx = wmax(s);
  float e = expf(s - mx);
  float Z = wsum(e);
  float c = e / Z;
  float cn2 = wsum(c*c);
  Smat[(size_t)node*NR + l] = c;
  Kbf[(size_t)node*NR + l] = f2bf(c * rsqrtf(cn2));
  __syncthreads();
  if(threadIdx.x==0){
    klp[blockIdx.x] = shk[0]+shk[1]+shk[2]+shk[3];
    mp [blockIdx.x] = shm[0]+shm[1]+shm[2]+shm[3];
  }
}

// ---- k_off: CSR offsets from prox popcounts (scan only, no dots) ----
// One wave per node row n. Lane L owns prox word L; diag bit OR'd in.
// off[n][t] = exclusive prefix at lane 2t ; off[n][32] = total.
__global__ __launch_bounds__(256) void k_off(const unsigned* __restrict__ prox,
                                             unsigned short* __restrict__ off){
  int w = threadIdx.x>>6, L = threadIdx.x&63;
  int n = blockIdx.x*4 + w;                    // global row in [0, NB*NN)
  int node = n & (NN-1);
  unsigned word = prox[(size_t)n*64 + L];
  if(L == (node>>5)) word |= 1u << (node&31);  // diagonal always present
  int pc = __popc(word);
  int pre = pc;                                 // inclusive scan
  #pragma unroll
  for(int o=1;o<64;o<<=1){
    int v = __shfl_up(pre, o, 64);
    if(L >= o) pre += v;
  }
  int base = pre - pc;                          // exclusive
  if((L&1)==0) off[(size_t)n*33 + (L>>1)] = (unsigned short)base;
  if(L==63)    off[(size_t)n*33 + 32]     = (unsigned short)pre;
}

// ---- k_qks: sparse P entries — dots via MFMA + prefix-compacted scatter ----
// grid 1024 (= 8b x 32qt x 4kc — round-11 bug was grid 4096: rogue kc>=4
// blocks scattered col-garbage). Wave w owns rows qt*64+w*16..+15.
// Per kt: 8 B-frag loads (L2-hot Kbf) + 8 MFMA -> pacc[f][r]; prox 16-bit
// fragment mask gives slot = base[r] + popc(m16 & below_li); set lanes
// write (col<<16)|bf16(val). base[r] starts at off[row][kc*8]. No barriers.
__global__ __launch_bounds__(256) void k_qks(const unsigned short* __restrict__ Kbf,
                                             const unsigned* __restrict__ prox,
                                             const unsigned short* __restrict__ off,
                                             unsigned* __restrict__ nbr){
  int tid = threadIdx.x;
  int w = tid>>6, l = tid&63, q = l>>4, li = l&15;
  int b  = blockIdx.x & 7;
  int qt = (blockIdx.x>>3) & 31;
  int kc = blockIdx.x >> 8;                   // 0..3 (chunk of 8 kts)
  const unsigned short* Kb = Kbf + (size_t)b*NN*NR;

  int arow = qt*64 + w*16 + li;
  bf16x8 af0 = *(const bf16x8*)(Kb + (size_t)arow*NR + q*8);
  bf16x8 af1 = *(const bf16x8*)(Kb + (size_t)arow*NR + 32 + q*8);

  // rows handled by this lane's (q)-group: lrow = w*16+q*4+r
  int base[4];
  #pragma unroll
  for(int r=0;r<4;r++)
    base[r] = off[(size_t)(b*NN + qt*64 + w*16 + q*4 + r)*33 + kc*8];

  unsigned below = (1u<<li) - 1u;

  #pragma unroll 1
  for(int kt = kc*8; kt < kc*8 + 8; ++kt){
    uint2 mw[4];
    #pragma unroll
    for(int r=0;r<4;r++)
      mw[r] = *(const uint2*)(prox + ((size_t)(b*NN + qt*64 + w*16 + q*4 + r))*64 + kt*2);
    if(qt==kt){
      #pragma unroll
      for(int r=0;r<4;r++){
        int lrow = w*16 + q*4 + r;
        if((lrow>>5)==0) mw[r].x |= 1u<<(lrow&31); else mw[r].y |= 1u<<(lrow&31);
      }
    }
    bf16x8 b0[4], b1[4];
    #pragma unroll
    for(int f=0;f<4;f++){
      const unsigned short* p = Kb + (size_t)(kt*64 + f*16 + li)*NR + q*8;
      b0[f] = *(const bf16x8*)p;
      b1[f] = *(const bf16x8*)(p + 32);
    }
    f32x4 pacc[4] = {(f32x4)(0.f),(f32x4)(0.f),(f32x4)(0.f),(f32x4)(0.f)};
    #pragma unroll
    for(int f=0;f<4;f++){
      pacc[f] = __builtin_amdgcn_mfma_f32_16x16x32_bf16(af0, b0[f], pacc[f], 0,0,0);
      pacc[f] = __builtin_amdgcn_mfma_f32_16x16x32_bf16(af1, b1[f], pacc[f], 0,0,0);
    }
    // compaction: per row r, fragments f ascending keep col order per tile
    #pragma unroll
    for(int r=0;r<4;r++){
      unsigned* nrow = nbr + (size_t)(b*NN + qt*64 + w*16 + q*4 + r)*NBCAP;
      #pragma unroll
      for(int f=0;f<4;f++){
        unsigned wd  = (f<2) ? mw[r].x : mw[r].y;
        unsigned m16 = (wd >> ((f&1)*16)) & 0xFFFFu;
        if(m16){
          if((m16 >> li) & 1u){
            int idx = base[r] + __popc(m16 & below);
            if(idx < NBCAP)
              nrow[idx] = ((unsigned)(kt*64 + f*16 + li) << 16) | (unsigned)f2bf(pacc[f][r]);
          }
          base[r] += __popc(m16);
        }
      }
    }
  }
}

// ---- k_pv: out = diag(1/(P*1)) P X. BK=64 swizzled skeleton; A-tile
// rebuilt per K-step by LDS scatter of sparse entries (P never in HBM).
// 2 barriers/step: thread (srow,g) zeros its OWN 32B of Al[srow] and then
// scatters into Al[srow] — same-wave DS ordering makes zero->scatter safe
// without a fence; cross-wave visibility is barrier B as before. ----
__global__ __launch_bounds__(256, 3) void k_pv(const unsigned* __restrict__ nbr,
                                               const unsigned short* __restrict__ off,
                                               const unsigned short* __restrict__ xTbf,
                                               float* __restrict__ out){
  __shared__ unsigned short Al[64*64];     // 8 KB  P-tile (scatter-built)
  __shared__ unsigned short Bl[128*64];    // 16 KB xT tile
  __shared__ unsigned short offL[64*33];   // 4.2 KB CSR offsets
  int tid = threadIdx.x;
  int w = tid>>6, l = tid&63, q = l>>4, li = l&15;
  int b  = blockIdx.x & 7;
  int mt = (blockIdx.x>>3) & 31;
  int ct = blockIdx.x >> 8;                // 0..2
  int m0 = mt*64;
  int d0 = ct*128;
  const unsigned short* xTb = xTbf + (size_t)b*ND*NN;

  int wr = w & 1, wc = w >> 1;

  int lrow8 = l>>3;
  int sgel  = ((l&7) ^ lrow8) * 8;
  const unsigned short* gsrc[4];
  unsigned short* ldst[4];
  #pragma unroll
  for(int j=0;j<4;j++){
    int id = w*4 + j;
    ldst[j] = Bl + id*512;
    gsrc[j] = xTb + (size_t)(d0 + id*8 + lrow8)*NN + sgel;
  }

  int srow = tid>>2, g = tid&3;
  int r7s  = srow & 7;
  const unsigned* ebase = nbr + (size_t)(b*NN + m0 + srow)*NBCAP;
  for(int j=g; j<33; j+=4)
    offL[srow*33 + j] = off[(size_t)(b*NN + m0 + srow)*33 + j];

  f32x4 acc[2][4];
  #pragma unroll
  for(int nc=0;nc<2;nc++)
    #pragma unroll
    for(int t=0;t<4;t++) acc[nc][t] = (f32x4)(0.f);
  f32x4 rs[2] = {(f32x4)(0.f),(f32x4)(0.f)};
  bf16x8 ones;
  #pragma unroll
  for(int i=0;i<8;i++) ones[i] = (short)0x3F80;   // bf16 1.0

  int r7 = li & 7;
  for(int k0=0; k0<NN; k0+=64){
    int t = k0 >> 6;
    __syncthreads();                       // A: prev PV reads done (+offL on t=0)
    // zero own 32B of Al[srow] (the only region this 4-lane group scatters
    // into; same-wave DS ordering -> no extra barrier needed)
    {
      uint4 z = {0,0,0,0};
      *(uint4*)&Al[srow*64 + g*16]     = z;
      *(uint4*)&Al[srow*64 + g*16 + 8] = z;
    }
    #pragma unroll
    for(int j=0;j<4;j++) gl2lds16(gsrc[j] + k0, ldst[j]);
    // scatter this tile's entries for row srow (guard col to protect LDS)
    {
      int s0 = offL[srow*33 + t];
      int s1 = offL[srow*33 + t + 1];
      if(s1 > NBCAP) s1 = NBCAP;
      for(int i=s0+g; i<s1; i+=4){
        unsigned e = ebase[i];
        int col = (int)(e >> 16) - k0;
        if((unsigned)col < 64u){
          int phys = (((col>>3) ^ r7s) << 3) | (col & 7);
          Al[srow*64 + phys] = (unsigned short)(e & 0xffffu);
        }
      }
    }
    __syncthreads();                       // B: Al visible + Bl drained

    #pragma unroll
    for(int s=0;s<2;s++){
      int ps = ((s*4 + q) ^ r7) * 8;       // swizzled read seg (elements)
      bf16x8 a0 = *(const bf16x8*)&Al[(wr*32 +      li)*64 + ps];
      bf16x8 a1 = *(const bf16x8*)&Al[(wr*32 + 16 + li)*64 + ps];
      bf16x8 bv[4];
      #pragma unroll
      for(int t2=0;t2<4;t2++)
        bv[t2] = *(const bf16x8*)&Bl[(wc*64 + t2*16 + li)*64 + ps];
      #pragma unroll
      for(int t2=0;t2<4;t2++){
        acc[0][t2] = __builtin_amdgcn_mfma_f32_16x16x32_bf16(a0, bv[t2], acc[0][t2], 0,0,0);
        acc[1][t2] = __builtin_amdgcn_mfma_f32_16x16x32_bf16(a1, bv[t2], acc[1][t2], 0,0,0);
      }
      rs[0] = __builtin_amdgcn_mfma_f32_16x16x32_bf16(a0, ones, rs[0], 0,0,0);
      rs[1] = __builtin_amdgcn_mfma_f32_16x16x32_bf16(a1, ones, rs[1], 0,0,0);
    }
  }

  #pragma unroll
  for(int nc=0;nc<2;nc++)
    #pragma unroll
    for(int r=0;r<4;r++){
      int row = m0 + wr*32 + nc*16 + q*4 + r;
      float inv = 1.f/(rs[nc][r] + 1e-8f);
      float* orow = out + ((size_t)(b*NN + row))*ND + d0 + wc*64;
      #pragma unroll
      for(int t2=0;t2<4;t2++)
        orow[t2*16 + li] = acc[nc][t2][r] * inv;
    }
}

// ---- segout; block 0 also reduces the loss partials ----
__global__ void k_segout(const int* __restrict__ seg, float* __restrict__ o,
                         const float* __restrict__ klp, const float* __restrict__ mp,
                         float* __restrict__ outLoss){
  int tid = threadIdx.x;
  int i = blockIdx.x*256 + tid;
  o[i] = (float)seg[i];
  if(blockIdx.x==0){
    __shared__ float sa[4], sm[4];
    float a=0.f, m=0.f;
    for(int k=tid; k<NBLK_LOSS; k+=256){ a += klp[k]; m += mp[k]; }
    a = wsum(a); m = wsum(m);
    if((tid&63)==0){ sa[tid>>6]=a; sm[tid>>6]=m; }
    __syncthreads();
    if(tid==0)
      outLoss[0] = (sa[0]+sa[1]+sa[2]+sa[3])/((sm[0]+sm[1]+sm[2]+sm[3])+1e-8f);
  }
}

extern "C" void kernel_launch(void* const* d_in, const int* in_sizes, int n_in,
                              void* d_out, int out_size, void* d_ws, size_t ws_size,
                              hipStream_t stream) {
  const float* x      = (const float*)d_in[0];
  const int*   seg    = (const int*)d_in[1];
  const float* protos = (const float*)d_in[2];

  float* out     = (float*)d_out;                  // (B,N,D)
  float* outSeg  = out + OUT_ELEMS;                // (B,H,W)
  float* outLoss = outSeg + SEG_ELEMS;             // scalar
  float* outC    = outLoss + 1;                    // (B,N,R)

  // ws layout (sparse P lists live in the old Pbf region)
  unsigned short* xTbf = (unsigned short*)d_ws;            // 8*384*2048 bf16 (12.6MB)
  unsigned short* Kbf  = xTbf + (size_t)NB*ND*NN;          // 8*2048*64 bf16 (2MB)
  unsigned short* Pbf  = Kbf + (size_t)NB*NN*NR;           // 64MB region, reused:
  unsigned*       nbr  = (unsigned*)Pbf;                   //   16384*384 u32 (25MB)
  unsigned short* off  = (unsigned short*)(nbr + (size_t)NB*NN*NBCAP); // 16384*33 u16
  float* kn      = (float*)(Pbf + (size_t)NB*NN*NN);       // 24576 f32
  float* maskp   = kn + NR*ND;                             // 16384  -- zero region (64KB)
  unsigned* prox = (unsigned*)(maskp + NB*NN);             // 8*2048*64 u32 (4MB, fully written)
  float* part    = (float*)(prox + (size_t)NB*NN*64);      // 8*32*64 (fully written)
  float* klp     = part + NB*32*64;                        // 4096 (fully written)
  float* mp      = klp + NBLK_LOSS;                        // 4096 (fully written)

  // only maskp needs zeroing (prox/nbr/off are fully written before use)
  hipMemsetAsync(maskp, 0, (size_t)NB*NN*4, stream);

  k_proto <<<dim3(NR),           dim3(64),   0, stream>>>(protos, kn);
  k_seg   <<<dim3(256),          dim3(1024), 0, stream>>>(seg, maskp, prox);
  k_csim  <<<dim3(NB*NN/64),     dim3(256),  0, stream>>>(x, kn, outC, xTbf, part);
  k_lossfc<<<dim3(NBLK_LOSS),    dim3(256),  0, stream>>>(outC, part, maskp, klp, mp, Kbf);
  k_off   <<<dim3(NB*NN/4),      dim3(256),  0, stream>>>(prox, off);
  k_qks   <<<dim3(1024),         dim3(256),  0, stream>>>(Kbf, prox, off, nbr);
  k_pv    <<<dim3(768),          dim3(256),  0, stream>>>(nbr, off, xTbf, out);
  k_segout<<<dim3(SEG_ELEMS/256),dim3(256),  0, stream>>>(seg, outSeg, klp, mp, outLoss);
}

// Round 13
// 215.483 us; speedup vs baseline: 2.7069x; 1.1050x over previous
//
#include <hip/hip_runtime.h>
#include <hip/hip_bf16.h>

// B=8, N=2048, D=384, R=64, H=W=256.
// Inputs:  x (B,N,D) f32, segments (B,H,W) i32, prototypes (1,R,D) f32.
// Outputs (f32, concat): out (B,N,D) | segments (B,H,W) | loss (1) | C (B,N,R)
//
// Pipeline (8 dispatches) — ROUND-8 PIPELINE (best: 216.5us) + k_qk 2-deep
// kt pipelining:
//   memset(maskp, 64KB) ; k_proto ; k_seg (LDS-bitmask build) ; k_csim ;
//   k_lossfc ; k_qk (P=mask.*ChatChat^T -> ws; barrier-free wave-autonomous
//   kt-panels, NOW 2-deep pipelined with double-buffered private LDS slice)
//   ; k_pv (dense BK=64 swizzled LDS-staged GEMM) ; k_segout.
//
// Round-12 lesson: sparse-P (k_off+k_qks+scatter-k_pv) = 238us — the
// per-K-step LDS scatter on the CONSUMER side (62us k_pv) eats more than
// the producer-side saving. Dense round-8 restored.
// k_qk lesson: round-8's `#pragma unroll 1` serialized the 4 per-wave kt
// chains (47.4us, nothing saturated). Explicit 2-pair interleave gives two
// independent load->MFMA->pack->store chains per wave.
#define NB 8
#define NN 2048
#define ND 384
#define NR 64
#define OUT_ELEMS (NB*NN*ND)        // 6291456
#define SEG_ELEMS (NB*256*256)      // 524288
#define NBLK_LOSS (NB*NN/4)         // 4096

typedef float  f32x4  __attribute__((ext_vector_type(4)));
typedef short  bf16x8 __attribute__((ext_vector_type(8)));

__device__ inline float wsum(float v){
  #pragma unroll
  for(int o=32;o;o>>=1) v += __shfl_xor(v,o,64);
  return v;
}
__device__ inline float wmax(float v){
  #pragma unroll
  for(int o=32;o;o>>=1) v = fmaxf(v,__shfl_xor(v,o,64));
  return v;
}
__device__ inline unsigned short f2bf(float f){
  unsigned u = __float_as_uint(f);
  return (unsigned short)((u + 0x8000u) >> 16);
}

// async global->LDS, 16 B per lane; LDS dest is wave-uniform base + lane*16
__device__ __forceinline__ void gl2lds16(const unsigned short* g, unsigned short* s){
  __builtin_amdgcn_global_load_lds(
      (const __attribute__((address_space(1))) unsigned int*)g,
      (__attribute__((address_space(3))) unsigned int*)s,
      16, 0, 0);
}

// ---- normalize prototypes -> kn (f32, unit rows) ----
__global__ void k_proto(const float* __restrict__ protos, float* __restrict__ kn){
  int r = blockIdx.x, l = threadIdx.x;
  float v[6]; float ss = 0.f;
  #pragma unroll
  for(int i=0;i<6;i++){ v[i] = protos[r*ND + l*6 + i]; ss += v[i]*v[i]; }
  ss = wsum(ss);
  float inv = 1.f / fmaxf(sqrtf(ss), 1e-8f);
  #pragma unroll
  for(int i=0;i<6;i++) kn[r*ND + l*6 + i] = v[i]*inv;
}

// ---- segments -> node mask + prox bitmask rows, built in LDS ----
// grid 256: b=bid&7 (batch), rg=bid>>3 (64-node range). 1024 threads.
__global__ __launch_bounds__(1024) void k_seg(const int* __restrict__ seg,
                                              float* __restrict__ mask,
                                              unsigned* __restrict__ prox){
  __shared__ unsigned lm[64*64];    // 16 KB
  int tid = threadIdx.x;
  int b  = blockIdx.x & 7;
  int rg = blockIdx.x >> 3;         // 0..31
  int base = rg << 6;
  for(int i=tid; i<64*64; i+=1024) lm[i] = 0u;
  __syncthreads();
  const int* sb = seg + b*65536;

#define PAIR(S, S2) { \
    if((S) != (S2) && (S) != 0 && (S2) != 0){ \
      if(((S )>>6)==rg) atomicOr(&lm[(((S )&63)<<6) + ((S2)>>5)], 1u<<((S2)&31)); \
      if(((S2)>>6)==rg) atomicOr(&lm[(((S2)&63)<<6) + ((S )>>5)], 1u<<((S )&31)); \
    } }

  #pragma unroll 1
  for(int it=0; it<16; ++it){
    int g = it*1024 + tid;          // int4 group index in [0,16384)
    int p = g*4;
    int i = g >> 6;                 // row 0..255
    int j = (g & 63)*4;             // col 0,4,...,252
    int4 a = *(const int4*)(sb + p);
    if((a.x>>6)==rg) mask[(b<<11) + a.x] = 1.f;
    if((a.y>>6)==rg) mask[(b<<11) + a.y] = 1.f;
    if((a.z>>6)==rg) mask[(b<<11) + a.z] = 1.f;
    if((a.w>>6)==rg) mask[(b<<11) + a.w] = 1.f;
    PAIR(a.x, a.y); PAIR(a.y, a.z); PAIR(a.z, a.w);
    if(j < 252){
      int n = sb[p + 4];
      PAIR(a.w, n);
    }
    if(i < 255){
      int4 v = *(const int4*)(sb + p + 256);
      PAIR(a.x, v.x); PAIR(a.y, v.y); PAIR(a.z, v.z); PAIR(a.w, v.w);
    }
  }
#undef PAIR
  __syncthreads();
  unsigned* dst = prox + ((size_t)(b<<11) + base)*64;
  *(uint4*)(dst + tid*4) = *(const uint4*)&lm[tid*4];
}

// ---- Csim GEMM: writes NORMALIZED s, colsum partials, bf16 xT ----
__global__ __launch_bounds__(256) void k_csim(const float* __restrict__ x,
                                              const float* __restrict__ kn,
                                              float* __restrict__ Sout,
                                              unsigned short* __restrict__ xTbf,
                                              float* __restrict__ part){
  __shared__ float xT[32*68];
  __shared__ float kT[32*68];
  __shared__ float xinvS[64];
  __shared__ float csh[16*64];
  int t = threadIdx.x;
  int m0 = blockIdx.x * 64;
  float acc[4][4] = {};
  int mload = t>>2, koff = (t&3)*8;
  int mb = (t>>4)*4, rb = (t&15)*4;
  float ssq = 0.f;
  for(int c=0;c<12;c++){
    int k0 = c*32;
    __syncthreads();
    const float4* xg = (const float4*)(x + (size_t)(m0+mload)*ND + k0 + koff);
    float4 a = xg[0], bq = xg[1];
    ssq += a.x*a.x + a.y*a.y + a.z*a.z + a.w*a.w
         + bq.x*bq.x + bq.y*bq.y + bq.z*bq.z + bq.w*bq.w;
    xT[(koff+0)*68+mload]=a.x;  xT[(koff+1)*68+mload]=a.y;  xT[(koff+2)*68+mload]=a.z;  xT[(koff+3)*68+mload]=a.w;
    xT[(koff+4)*68+mload]=bq.x; xT[(koff+5)*68+mload]=bq.y; xT[(koff+6)*68+mload]=bq.z; xT[(koff+7)*68+mload]=bq.w;
    const float4* kg = (const float4*)(kn + mload*ND + k0 + koff);
    float4 ka = kg[0], kb = kg[1];
    kT[(koff+0)*68+mload]=ka.x; kT[(koff+1)*68+mload]=ka.y; kT[(koff+2)*68+mload]=ka.z; kT[(koff+3)*68+mload]=ka.w;
    kT[(koff+4)*68+mload]=kb.x; kT[(koff+5)*68+mload]=kb.y; kT[(koff+6)*68+mload]=kb.z; kT[(koff+7)*68+mload]=kb.w;
    __syncthreads();
    {
      int k2 = t>>3, mo = (t&7)*8;
      const float* src = &xT[k2*68 + mo];
      float4 aa = *(const float4*)src;
      float4 bb = *(const float4*)(src+4);
      uint4 o;
      o.x = (unsigned)f2bf(aa.x) | ((unsigned)f2bf(aa.y)<<16);
      o.y = (unsigned)f2bf(aa.z) | ((unsigned)f2bf(aa.w)<<16);
      o.z = (unsigned)f2bf(bb.x) | ((unsigned)f2bf(bb.y)<<16);
      o.w = (unsigned)f2bf(bb.z) | ((unsigned)f2bf(bb.w)<<16);
      int bb2 = m0 >> 11, ml = m0 & 2047;
      *(uint4*)(xTbf + ((size_t)(bb2*ND + k0 + k2))*NN + ml + mo) = o;
    }
    for(int k=0;k<32;k++){
      float xv[4], kv[4];
      *(float4*)xv = *(const float4*)&xT[k*68+mb];
      *(float4*)kv = *(const float4*)&kT[k*68+rb];
      #pragma unroll
      for(int mi=0;mi<4;mi++)
        #pragma unroll
        for(int ri=0;ri<4;ri++) acc[mi][ri] += xv[mi]*kv[ri];
    }
  }
  ssq += __shfl_xor(ssq,1,64);
  ssq += __shfl_xor(ssq,2,64);
  if((t&3)==0) xinvS[mload] = 1.f / fmaxf(sqrtf(ssq), 1e-8f);
  __syncthreads();
  float sv[4][4];
  #pragma unroll
  for(int mi=0;mi<4;mi++){
    float xin = xinvS[mb+mi];
    float rsum = 0.f;
    #pragma unroll
    for(int ri=0;ri<4;ri++){
      float vv = (acc[mi][ri]*xin + 1.f)*0.5f;
      sv[mi][ri] = vv; rsum += vv;
    }
    rsum += __shfl_xor(rsum,1,64);
    rsum += __shfl_xor(rsum,2,64);
    rsum += __shfl_xor(rsum,4,64);
    rsum += __shfl_xor(rsum,8,64);
    float inv = 1.f/rsum;
    #pragma unroll
    for(int ri=0;ri<4;ri++) sv[mi][ri] *= inv;
    *(float4*)&Sout[(size_t)(m0+mb+mi)*NR + rb] = *(const float4*)sv[mi];
  }
  {
    float4 pc;
    pc.x = sv[0][0]+sv[1][0]+sv[2][0]+sv[3][0];
    pc.y = sv[0][1]+sv[1][1]+sv[2][1]+sv[3][1];
    pc.z = sv[0][2]+sv[1][2]+sv[2][2]+sv[3][2];
    pc.w = sv[0][3]+sv[1][3]+sv[2][3]+sv[3][3];
    *(float4*)&csh[(t>>4)*64 + rb] = pc;
  }
  __syncthreads();
  if(t < 64){
    float a = 0.f;
    #pragma unroll
    for(int g=0;g<16;g++) a += csh[g*64 + t];
    part[(size_t)blockIdx.x*64 + t] = a;        // part[b*32+chunk][r]
  }
}

// ---- DEC KL loss (partial stores) + C=softmax(s) in place + Kbf ----
__global__ void k_lossfc(float* Smat, const float* __restrict__ part,
                         const float* __restrict__ mask,
                         float* __restrict__ klp, float* __restrict__ mp,
                         unsigned short* __restrict__ Kbf){
  __shared__ float shk[4], shm[4];
  int w = threadIdx.x>>6, l = threadIdx.x&63;
  int node = blockIdx.x*4 + w;
  int b = node >> 11;
  float s = Smat[(size_t)node*NR + l];
  float csm = 0.f;
  #pragma unroll
  for(int c=0;c<32;c++) csm += part[(size_t)((b<<5)+c)*64 + l];
  float p = s*s/(csm + 1e-8f);
  float ps = wsum(p);
  float P = p/(ps + 1e-8f);
  float term = P*(logf(P + 1e-8f) - logf(s + 1e-8f));
  float kl = wsum(term);
  if(l==0){ float mv = mask[node]; shk[w] = kl*mv; shm[w] = mv; }
  float mx = wmax(s);
  float e = expf(s - mx);
  float Z = wsum(e);
  float c = e / Z;
  float cn2 = wsum(c*c);
  Smat[(size_t)node*NR + l] = c;
  Kbf[(size_t)node*NR + l] = f2bf(c * rsqrtf(cn2));
  __syncthreads();
  if(threadIdx.x==0){
    klp[blockIdx.x] = shk[0]+shk[1]+shk[2]+shk[3];
    mp [blockIdx.x] = shm[0]+shm[1]+shm[2]+shm[3];
  }
}

// ---- pass A: P = mask .* (Chat Chat^T), bf16 -> ws. BARRIER-FREE,
// 2-DEEP kt PIPELINE ----
// grid 2048: b=bid&7, qt=(bid>>3)&31, kc=bid>>8 (kt chunk of 4).
// Wave w owns rows qt*64+w*16..+15 for all 4 kts; kts processed in PAIRS
// with double-buffered private LDS slices: both kts' loads issued, then
// both MFMA groups, then both packs (separate bufs), then both stores —
// two independent chains in flight (round-8's `unroll 1` forbade this;
// each wave ran 4 serial load->MFMA->pack->lgkm->store chains).
__global__ __launch_bounds__(256) void k_qk(const unsigned short* __restrict__ Kbf,
                                            const unsigned* __restrict__ prox,
                                            unsigned short* __restrict__ Pbf){
  __shared__ short Plds[4][2][16*72];   // 4 waves x 2 bufs x 2304B = 18.4 KB
  int tid = threadIdx.x;
  int w = tid>>6, l = tid&63, q = l>>4, li = l&15;
  int b  = blockIdx.x & 7;
  int qt = (blockIdx.x>>3) & 31;
  int kc = blockIdx.x >> 8;          // 0..7 (chunk of 4 kts)
  const unsigned short* Kb = Kbf + (size_t)b*NN*NR;

  int arow = qt*64 + w*16 + li;
  bf16x8 af0 = *(const bf16x8*)(Kb + (size_t)arow*NR + q*8);
  bf16x8 af1 = *(const bf16x8*)(Kb + (size_t)arow*NR + 32 + q*8);

  int srow = l>>2, sg = l&3;         // store: row-in-wave 0..15, 16B seg 0..3

#define QK_LOAD(KT, MW, B0, B1) { \
    _Pragma("unroll") for(int r=0;r<4;r++) \
      MW[r] = *(const uint2*)(prox + ((size_t)(b*NN + qt*64 + w*16 + q*4 + r))*64 + (KT)*2); \
    _Pragma("unroll") for(int f=0;f<4;f++){ \
      const unsigned short* p = Kb + (size_t)((KT)*64 + f*16 + li)*NR + q*8; \
      B0[f] = *(const bf16x8*)p; B1[f] = *(const bf16x8*)(p + 32); } }

#define QK_MFMA(PACC, B0, B1) { \
    _Pragma("unroll") for(int f=0;f<4;f++){ \
      PACC[f] = __builtin_amdgcn_mfma_f32_16x16x32_bf16(af0, B0[f], PACC[f], 0,0,0); \
      PACC[f] = __builtin_amdgcn_mfma_f32_16x16x32_bf16(af1, B1[f], PACC[f], 0,0,0); } }

#define QK_PACK(KT, MW, PACC, BUF) { \
    _Pragma("unroll") for(int r=0;r<4;r++){ \
      int lrow = q*4 + r; \
      int brow = w*16 + lrow; \
      uint2 m = MW[r]; \
      if(qt==(KT)){ \
        if((brow>>5)==0) m.x |= 1u<<(brow&31); else m.y |= 1u<<(brow&31); } \
      _Pragma("unroll") for(int f=0;f<4;f++){ \
        unsigned wd = (f<2) ? m.x : m.y; \
        float v = ((wd >> ((f&1)*16 + li)) & 1u) ? PACC[f][r] : 0.f; \
        Plds[w][BUF][lrow*72 + f*16 + li] = (short)f2bf(v); } } }

#define QK_STORE(KT, BUF) { \
    const uint4* src = (const uint4*)&Plds[w][BUF][srow*72 + sg*16]; \
    unsigned short* dst = Pbf + ((size_t)(b*NN + qt*64 + w*16 + srow))*NN + (KT)*64 + sg*16; \
    uint4 v0 = src[0], v1 = *(const uint4*)((const short*)src + 8); \
    *(uint4*)dst = v0; \
    *(uint4*)(dst + 8) = v1; }

  #pragma unroll 1
  for(int kt = kc*4; kt < kc*4 + 4; kt += 2){
    uint2 mw0[4], mw1[4];
    bf16x8 b00[4], b01[4], b10[4], b11[4];
    QK_LOAD(kt,   mw0, b00, b01);
    QK_LOAD(kt+1, mw1, b10, b11);
    f32x4 p0[4] = {(f32x4)(0.f),(f32x4)(0.f),(f32x4)(0.f),(f32x4)(0.f)};
    f32x4 p1[4] = {(f32x4)(0.f),(f32x4)(0.f),(f32x4)(0.f),(f32x4)(0.f)};
    QK_MFMA(p0, b00, b01);
    QK_MFMA(p1, b10, b11);
    QK_PACK(kt,   mw0, p0, 0);
    QK_PACK(kt+1, mw1, p1, 1);
    QK_STORE(kt,   0);
    QK_STORE(kt+1, 1);
  }
#undef QK_LOAD
#undef QK_MFMA
#undef QK_PACK
#undef QK_STORE
}

// ---- pass B: out = diag(1/(P*1)) P X — LDS-staged GEMM, BK=64, swizzled ----
// BM=64, BN=128, BK=64. grid 768: b=bid&7, mt=(bid>>3)&31, ct=bid>>8.
// 4 waves: wave (wr=w&1, wc=w>>1) owns 32 rows x 64 cols. Per K-step:
// 24 gl2lds(1KB chunks: A 8 + B 16, 6/wave) ; barrier ; 2 k-subs x
// (6 ds_read_b128 + 10 MFMA). LDS 24KB -> 3 blocks/CU.
// Swizzle (rule #21): LDS dest linear; global src seg pre-swizzled
// seg_g=(l&7)^(l>>3); ds_read phys seg = (s*4+q)^(row&7) -> 2-way banks.
__global__ __launch_bounds__(256, 3) void k_pv(const unsigned short* __restrict__ Pbf,
                                               const unsigned short* __restrict__ xTbf,
                                               float* __restrict__ out){
  __shared__ unsigned short Al[64*64];     // 8 KB  (64 rows x 128B)
  __shared__ unsigned short Bl[128*64];    // 16 KB (128 rows x 128B)
  int tid = threadIdx.x;
  int w = tid>>6, l = tid&63, q = l>>4, li = l&15;
  int b  = blockIdx.x & 7;
  int mt = (blockIdx.x>>3) & 31;
  int ct = blockIdx.x >> 8;                // 0..2
  int m0 = mt*64;
  int d0 = ct*128;
  const unsigned short* Pb  = Pbf  + (size_t)b*NN*NN;
  const unsigned short* xTb = xTbf + (size_t)b*ND*NN;

  int wr = w & 1, wc = w >> 1;

  // staging: 24 chunks of 1KB (A: 0-7, B: 8-23); wave w issues chunks
  // w*6..w*6+5. Chunk = 8 rows x 128B; lane l -> row c*8+(l>>3), LDS linear
  // l*16; global source seg PRE-SWIZZLED: seg_g = (l&7) ^ (l>>3).
  int lrow8 = l>>3;
  int sgel  = ((l&7) ^ lrow8) * 8;         // swizzled 16B-seg, in elements
  const unsigned short* gsrc[6];
  unsigned short* ldst[6];
  #pragma unroll
  for(int j=0;j<6;j++){
    int id = w*6 + j;
    if(id < 8){
      ldst[j] = Al + id*512;
      gsrc[j] = Pb + (size_t)(m0 + id*8 + lrow8)*NN + sgel;
    }else{
      ldst[j] = Bl + (id-8)*512;
      gsrc[j] = xTb + (size_t)(d0 + (id-8)*8 + lrow8)*NN + sgel;
    }
  }

  f32x4 acc[2][4];
  #pragma unroll
  for(int nc=0;nc<2;nc++)
    #pragma unroll
    for(int t=0;t<4;t++) acc[nc][t] = (f32x4)(0.f);
  f32x4 rs[2] = {(f32x4)(0.f),(f32x4)(0.f)};
  bf16x8 ones;
  #pragma unroll
  for(int i=0;i<8;i++) ones[i] = (short)0x3F80;   // bf16 1.0

  int r7 = li & 7;                         // row&7 for all this wave's frag rows
  for(int k0=0; k0<NN; k0+=64){
    __syncthreads();                       // previous compute done (LDS reuse)
    #pragma unroll
    for(int j=0;j<6;j++) gl2lds16(gsrc[j] + k0, ldst[j]);
    __syncthreads();                       // staging visible (vmcnt drain)
    #pragma unroll
    for(int s=0;s<2;s++){
      int ps = ((s*4 + q) ^ r7) * 8;       // swizzled read seg (elements)
      bf16x8 a0 = *(const bf16x8*)&Al[(wr*32 +      li)*64 + ps];
      bf16x8 a1 = *(const bf16x8*)&Al[(wr*32 + 16 + li)*64 + ps];
      bf16x8 bv[4];
      #pragma unroll
      for(int t=0;t<4;t++)
        bv[t] = *(const bf16x8*)&Bl[(wc*64 + t*16 + li)*64 + ps];
      #pragma unroll
      for(int t=0;t<4;t++){
        acc[0][t] = __builtin_amdgcn_mfma_f32_16x16x32_bf16(a0, bv[t], acc[0][t], 0,0,0);
        acc[1][t] = __builtin_amdgcn_mfma_f32_16x16x32_bf16(a1, bv[t], acc[1][t], 0,0,0);
      }
      rs[0] = __builtin_amdgcn_mfma_f32_16x16x32_bf16(a0, ones, rs[0], 0,0,0);
      rs[1] = __builtin_amdgcn_mfma_f32_16x16x32_bf16(a1, ones, rs[1], 0,0,0);
    }
  }

  #pragma unroll
  for(int nc=0;nc<2;nc++)
    #pragma unroll
    for(int r=0;r<4;r++){
      int row = m0 + wr*32 + nc*16 + q*4 + r;
      float inv = 1.f/(rs[nc][r] + 1e-8f);
      float* orow = out + ((size_t)(b*NN + row))*ND + d0 + wc*64;
      #pragma unroll
      for(int t=0;t<4;t++)
        orow[t*16 + li] = acc[nc][t][r] * inv;
    }
}

// ---- segout; block 0 also reduces the loss partials ----
__global__ void k_segout(const int* __restrict__ seg, float* __restrict__ o,
                         const float* __restrict__ klp, const float* __restrict__ mp,
                         float* __restrict__ outLoss){
  int tid = threadIdx.x;
  int i = blockIdx.x*256 + tid;
  o[i] = (float)seg[i];
  if(blockIdx.x==0){
    __shared__ float sa[4], sm[4];
    float a=0.f, m=0.f;
    for(int k=tid; k<NBLK_LOSS; k+=256){ a += klp[k]; m += mp[k]; }
    a = wsum(a); m = wsum(m);
    if((tid&63)==0){ sa[tid>>6]=a; sm[tid>>6]=m; }
    __syncthreads();
    if(tid==0)
      outLoss[0] = (sa[0]+sa[1]+sa[2]+sa[3])/((sm[0]+sm[1]+sm[2]+sm[3])+1e-8f);
  }
}

extern "C" void kernel_launch(void* const* d_in, const int* in_sizes, int n_in,
                              void* d_out, int out_size, void* d_ws, size_t ws_size,
                              hipStream_t stream) {
  const float* x      = (const float*)d_in[0];
  const int*   seg    = (const int*)d_in[1];
  const float* protos = (const float*)d_in[2];

  float* out     = (float*)d_out;                  // (B,N,D)
  float* outSeg  = out + OUT_ELEMS;                // (B,H,W)
  float* outLoss = outSeg + SEG_ELEMS;             // scalar
  float* outC    = outLoss + 1;                    // (B,N,R)

  // ws layout (~83 MB)
  unsigned short* xTbf = (unsigned short*)d_ws;            // 8*384*2048 bf16 (12.6MB)
  unsigned short* Kbf  = xTbf + (size_t)NB*ND*NN;          // 8*2048*64 bf16 (2MB)
  unsigned short* Pbf  = Kbf + (size_t)NB*NN*NR;           // 8*2048*2048 bf16 (64MB)
  float* kn      = (float*)(Pbf + (size_t)NB*NN*NN);       // 24576 f32
  float* maskp   = kn + NR*ND;                             // 16384  -- zero region (64KB)
  unsigned* prox = (unsigned*)(maskp + NB*NN);             // 8*2048*64 u32 (4MB, fully written by k_seg)
  float* part    = (float*)(prox + (size_t)NB*NN*64);      // 8*32*64 (fully written)
  float* klp     = part + NB*32*64;                        // 4096 (fully written)
  float* mp      = klp + NBLK_LOSS;                        // 4096 (fully written)

  // only maskp needs zeroing (prox is fully written by k_seg)
  hipMemsetAsync(maskp, 0, (size_t)NB*NN*4, stream);

  k_proto <<<dim3(NR),           dim3(64),   0, stream>>>(protos, kn);
  k_seg   <<<dim3(256),          dim3(1024), 0, stream>>>(seg, maskp, prox);
  k_csim  <<<dim3(NB*NN/64),     dim3(256),  0, stream>>>(x, kn, outC, xTbf, part);
  k_lossfc<<<dim3(NBLK_LOSS),    dim3(256),  0, stream>>>(outC, part, maskp, klp, mp, Kbf);
  k_qk    <<<dim3(2048),         dim3(256),  0, stream>>>(Kbf, prox, Pbf);
  k_pv    <<<dim3(768),          dim3(256),  0, stream>>>(Pbf, xTbf, out);
  k_segout<<<dim3(SEG_ELEMS/256),dim3(256),  0, stream>>>(seg, outSeg, klp, mp, outLoss);
}